// Round 7
// baseline (355.440 us; speedup 1.0000x reference)
//
#include <hip/hip_runtime.h>

#define NND 100000
#define NE  1600000
#define ET  (NE + NND)      // 1,700,000 edges incl. self loops
#define HD  128
#define NGR 64
#define NEG 0.2f

#define PEB   16384                     // edges per partition block
#define PBLK  ((ET + PEB - 1) / PEB)    // 104
#define NBK   ((NND + 511) / 512)       // 196 buckets of 512 nodes

typedef __attribute__((ext_vector_type(8))) short short8;
typedef __attribute__((ext_vector_type(4))) float f32x4;

__device__ __forceinline__ unsigned f2bf(float x) {
  unsigned u = __builtin_bit_cast(unsigned, x);
  return (u + 0x7fffu + ((u >> 16) & 1u)) >> 16;   // RNE, finite inputs
}
__device__ __forceinline__ float bflo(unsigned u) { return __builtin_bit_cast(float, u << 16); }
__device__ __forceinline__ float bfhi(unsigned u) { return __builtin_bit_cast(float, u & 0xffff0000u); }

// ---------------- W transpose to bf16 [col][k] (one-off, 32 KB, L2-resident) --------
__global__ void k_wt(const float* __restrict__ W, unsigned short* __restrict__ WT) {
  int t = blockIdx.x * 256 + threadIdx.x;   // 0..16383
  int c = t >> 7, k = t & 127;
  WT[t] = (unsigned short)f2bf(W[k * HD + c]);
}

// ---------------- GEMM: h = x @ W via bf16 MFMA, fused a_s/a_d dots ----------------
__global__ __launch_bounds__(256) void k_gemm(const float* __restrict__ x,
                                              const unsigned short* __restrict__ WT,
                                              const float* __restrict__ att_s,
                                              const float* __restrict__ att_d,
                                              unsigned* __restrict__ h_bf,
                                              float* __restrict__ a_s,
                                              float* __restrict__ a_d) {
  const int t = threadIdx.x;
  const int wv = t >> 6, l = t & 63;
  const int lr = l & 15, lk = l >> 4;
  const int arow = blockIdx.x * 64 + wv * 16 + lr;     // A-row this lane feeds
  const bool av = arow < NND;
  const float* xrow = x + (size_t)(av ? arow : 0) * HD;
  f32x4 acc[8];
#pragma unroll
  for (int j = 0; j < 8; ++j) acc[j] = (f32x4){0.f, 0.f, 0.f, 0.f};
#pragma unroll 1
  for (int s = 0; s < 4; ++s) {
    const int k0 = s * 32 + lk * 8;
    float4 x0 = av ? *(const float4*)&xrow[k0]     : make_float4(0.f, 0.f, 0.f, 0.f);
    float4 x1 = av ? *(const float4*)&xrow[k0 + 4] : make_float4(0.f, 0.f, 0.f, 0.f);
    short8 af;
    af[0] = (short)f2bf(x0.x); af[1] = (short)f2bf(x0.y);
    af[2] = (short)f2bf(x0.z); af[3] = (short)f2bf(x0.w);
    af[4] = (short)f2bf(x1.x); af[5] = (short)f2bf(x1.y);
    af[6] = (short)f2bf(x1.z); af[7] = (short)f2bf(x1.w);
#pragma unroll
    for (int j = 0; j < 8; ++j) {
      short8 bf8 = *(const short8*)&WT[(size_t)(j * 16 + lr) * HD + k0];
      acc[j] = __builtin_amdgcn_mfma_f32_16x16x32_bf16(af, bf8, acc[j], 0, 0, 0);
    }
  }
  float asv[8], adv[8];
#pragma unroll
  for (int j = 0; j < 8; ++j) { asv[j] = att_s[j * 16 + lr]; adv[j] = att_d[j * 16 + lr]; }
  float pa[4] = {0.f, 0.f, 0.f, 0.f}, pd[4] = {0.f, 0.f, 0.f, 0.f};
#pragma unroll
  for (int j = 0; j < 8; ++j)
#pragma unroll
    for (int r = 0; r < 4; ++r) {
      pa[r] = fmaf(acc[j][r], asv[j], pa[r]);
      pd[r] = fmaf(acc[j][r], adv[j], pd[r]);
    }
#pragma unroll
  for (int o = 1; o < 16; o <<= 1)
#pragma unroll
    for (int r = 0; r < 4; ++r) {
      pa[r] += __shfl_xor(pa[r], o);
      pd[r] += __shfl_xor(pd[r], o);
    }
  const int rbase = blockIdx.x * 64 + wv * 16 + lk * 4;   // D-rows this lane owns
#pragma unroll
  for (int r = 0; r < 4; ++r) {
    int row = rbase + r;
    if (row < NND && lr == 0) { a_s[row] = pa[r]; a_d[row] = pd[r]; }
  }
#pragma unroll
  for (int j = 0; j < 8; ++j)
#pragma unroll
    for (int r = 0; r < 4; ++r) {
      float v = acc[j][r];
      float vn = __shfl_xor(v, 1);
      int row = rbase + r;
      if ((lr & 1) == 0 && row < NND) {
        unsigned w = f2bf(v) | (f2bf(vn) << 16);
        h_bf[(size_t)row * 64 + ((j * 16 + lr) >> 1)] = w;
      }
    }
}

// ---------------- radix partition pass 1: per-block 256-bucket histogram ----------------
__global__ __launch_bounds__(1024) void k_hist(const int* __restrict__ ei,
                                               int* __restrict__ hist) {
  __shared__ int hcnt[256];
  const int t = threadIdx.x;
  if (t < 256) hcnt[t] = 0;
  __syncthreads();
  const int base = blockIdx.x * PEB;
#pragma unroll
  for (int i = 0; i < PEB / 1024; ++i) {
    int e = base + i * 1024 + t;
    if (e < ET) {
      int d = (e < NE) ? ei[NE + e] : (e - NE);
      atomicAdd(&hcnt[d >> 9], 1);
    }
  }
  __syncthreads();
  if (t < 256) hist[blockIdx.x * 256 + t] = hcnt[t];
}

// ---------------- pass 2: hist -> absolute chunk offsets; bucket ranges ----------------
__global__ __launch_bounds__(256) void k_hoff(int* __restrict__ hist,
                                              int* __restrict__ bkoff,
                                              int* __restrict__ bkcnt) {
  __shared__ int sm[2][256];
  const int t = threadIdx.x;   // bucket
  int run = 0;
  for (int b = 0; b < PBLK; ++b) {
    int v = hist[b * 256 + t];
    hist[b * 256 + t] = run;
    run += v;
  }
  sm[0][t] = run;
  __syncthreads();
  int c = 0;
  for (int o = 1; o < 256; o <<= 1) {
    int val = sm[c][t];
    if (t >= o) val += sm[c][t - o];
    sm[c ^ 1][t] = val;
    c ^= 1;
    __syncthreads();
  }
  int bstart = sm[c][t] - run;
  bkoff[t] = bstart;
  bkcnt[t] = run;
  for (int b = 0; b < PBLK; ++b) hist[b * 256 + t] += bstart;
}

// ---------------- pass 3: write (src,dst) bucket-major, contiguous chunks ----------------
__global__ __launch_bounds__(1024) void k_part(const int* __restrict__ ei,
                                               const int* __restrict__ hist,
                                               uint2* __restrict__ part) {
  __shared__ int hcur[256];
  const int t = threadIdx.x;
  if (t < 256) hcur[t] = hist[blockIdx.x * 256 + t];
  __syncthreads();
  const int base = blockIdx.x * PEB;
#pragma unroll
  for (int i = 0; i < PEB / 1024; ++i) {
    int e = base + i * 1024 + t;
    if (e < ET) {
      int s, d;
      if (e < NE) { s = ei[e]; d = ei[NE + e]; } else { s = e - NE; d = s; }
      int pos = atomicAdd(&hcur[d >> 9], 1);
      part[pos] = make_uint2((unsigned)s, (unsigned)d);
    }
  }
}

// ---------------- per-bucket degree count (LDS, one block per bucket) ----------------
__global__ __launch_bounds__(256) void k_bdeg(const uint2* __restrict__ part,
                                              const int* __restrict__ bkoff,
                                              const int* __restrict__ bkcnt,
                                              int* __restrict__ deg) {
  __shared__ int dcnt[512];
  const int t = threadIdx.x;
  const int b = blockIdx.x;
  dcnt[t] = 0; dcnt[t + 256] = 0;
  __syncthreads();
  const int lo = bkoff[b], n = bkcnt[b];
  for (int i = t; i < n; i += 256)
    atomicAdd(&dcnt[part[lo + i].y & 511], 1);
  __syncthreads();
#pragma unroll
  for (int j = t; j < 512; j += 256) {
    int node = b * 512 + j;
    if (node < NND) deg[node] = dcnt[j];
  }
}

// ---------------- exclusive scan of deg -> off ----------------
__global__ __launch_bounds__(256) void k_scan1(const int* __restrict__ deg,
                                               int* __restrict__ off,
                                               int* __restrict__ bsum) {
  __shared__ int sm[2][256];
  int t = threadIdx.x;
  int i = blockIdx.x * 256 + t;
  int v = (i < NND) ? deg[i] : 0;
  sm[0][t] = v;
  __syncthreads();
  int c = 0;
  for (int o = 1; o < 256; o <<= 1) {
    int val = sm[c][t];
    if (t >= o) val += sm[c][t - o];
    sm[c ^ 1][t] = val;
    c ^= 1;
    __syncthreads();
  }
  int incl = sm[c][t];
  if (i < NND) off[i] = incl - v;
  if (t == 255) bsum[blockIdx.x] = incl;
}

__global__ __launch_bounds__(512) void k_scan2(int* __restrict__ bsum) {
  __shared__ int sm[2][512];
  const int NB = 391;
  int t = threadIdx.x;
  int v = (t < NB) ? bsum[t] : 0;
  sm[0][t] = v;
  __syncthreads();
  int c = 0;
  for (int o = 1; o < 512; o <<= 1) {
    int val = sm[c][t];
    if (t >= o) val += sm[c][t - o];
    sm[c ^ 1][t] = val;
    c ^= 1;
    __syncthreads();
  }
  if (t < NB) bsum[t] = sm[c][t] - v;
}

__global__ void k_scan3(const int* __restrict__ bsum, int* __restrict__ off) {
  int i = blockIdx.x * 256 + threadIdx.x;
  if (i < NND) off[i] += bsum[blockIdx.x];
}

// ---------------- per-bucket exact scatter (LDS cursors, one block per bucket) --------
__global__ __launch_bounds__(256) void k_bscat(const uint2* __restrict__ part,
                                               const int* __restrict__ bkoff,
                                               const int* __restrict__ bkcnt,
                                               const int* __restrict__ off,
                                               int* __restrict__ esrc) {
  __shared__ int curl[512];
  const int t = threadIdx.x;
  const int b = blockIdx.x;
#pragma unroll
  for (int j = t; j < 512; j += 256) {
    int node = b * 512 + j;
    curl[j] = (node < NND) ? off[node] : 0;
  }
  __syncthreads();
  const int lo = bkoff[b], n = bkcnt[b];
  for (int i = t; i < n; i += 256) {
    uint2 e = part[lo + i];
    int pos = atomicAdd(&curl[e.y & 511], 1);
    esrc[pos] = (int)e.x;
  }
}

// ---------------- single-pass softmax-aggregate + silu ----------------
// wave per node; 4 edge-groups x 16 col-lanes; shfl-free (per-group redundant
// scalar compute) + 1-deep prefetch of next edge's (src, a_s).
__global__ __launch_bounds__(256) void k_agg(const int* __restrict__ off,
                                             const int* __restrict__ deg,
                                             const int* __restrict__ esrc,
                                             const float* __restrict__ a_s,
                                             const float* __restrict__ a_d,
                                             const unsigned* __restrict__ hb,
                                             const float* __restrict__ bias,
                                             unsigned* __restrict__ gnn) {
  int wid = (blockIdx.x * 256 + threadIdx.x) >> 6;
  int lane = threadIdx.x & 63;
  if (wid >= NND) return;
  const int grp = lane >> 4;     // edge slot 0..3
  const int lc  = lane & 15;     // col chunk: 4 words = 8 cols
  int start = off[wid];
  int ne = deg[wid];             // >= 1 (self loop)
  float adn = a_d[wid];
  float acc[8] = {};
  float ssum = 0.f;
  // prefetch slot for first iteration (clamped; masked by ev=0 later)
  int i0 = (grp < ne) ? grp : (ne - 1);
  int snx = esrc[start + i0];
  float asn = a_s[snx];
  for (int jj = 0; jj < ne; jj += 4) {
    const int icur = jj + grp;
    const bool act = icur < ne;
    const int scur = snx;
    const float asc = asn;
    const int in2 = icur + 4;
    if (in2 < ne) {              // 1-deep software pipeline
      snx = esrc[start + in2];
      asn = a_s[snx];
    }
    float e = asc + adn;
    e = (e > 0.f) ? e : NEG * e;
    float ev = act ? __expf(e) : 0.f;   // identical across the 16 group lanes
    ssum += ev;
    uint4 u = *((const uint4*)(hb + ((size_t)scur << 6)) + lc);
    acc[0] = fmaf(ev, bflo(u.x), acc[0]);
    acc[1] = fmaf(ev, bfhi(u.x), acc[1]);
    acc[2] = fmaf(ev, bflo(u.y), acc[2]);
    acc[3] = fmaf(ev, bfhi(u.y), acc[3]);
    acc[4] = fmaf(ev, bflo(u.z), acc[4]);
    acc[5] = fmaf(ev, bfhi(u.z), acc[5]);
    acc[6] = fmaf(ev, bflo(u.w), acc[6]);
    acc[7] = fmaf(ev, bfhi(u.w), acc[7]);
  }
  // groups hold identical ssum partials -> reduce across groups only
  ssum += __shfl_xor(ssum, 16);
  ssum += __shfl_xor(ssum, 32);
#pragma unroll
  for (int r = 0; r < 8; ++r) {
    acc[r] += __shfl_xor(acc[r], 16);
    acc[r] += __shfl_xor(acc[r], 32);
  }
  if (grp == 0) {
    float inv = 1.f / ssum;
    float4 b0 = *(const float4*)&bias[lc * 8];
    float4 b1 = *(const float4*)&bias[lc * 8 + 4];
    float bb[8] = {b0.x, b0.y, b0.z, b0.w, b1.x, b1.y, b1.z, b1.w};
    float g[8];
#pragma unroll
    for (int r = 0; r < 8; ++r) {
      float v = acc[r] * inv + bb[r];
      g[r] = v / (1.f + __expf(-v));
    }
    unsigned w0 = f2bf(g[0]) | (f2bf(g[1]) << 16);
    unsigned w1 = f2bf(g[2]) | (f2bf(g[3]) << 16);
    unsigned w2 = f2bf(g[4]) | (f2bf(g[5]) << 16);
    unsigned w3 = f2bf(g[6]) | (f2bf(g[7]) << 16);
    *(uint4*)&gnn[(size_t)wid * 64 + lc * 4] = make_uint4(w0, w1, w2, w3);
  }
}

// ---------------- per-graph mean pool (batch sorted, run accumulation) ----------------
__global__ __launch_bounds__(256) void k_pool(const unsigned* __restrict__ gnn,
                                              const int* __restrict__ batch,
                                              float* __restrict__ pooled,
                                              float* __restrict__ cnt) {
  int t = threadIdx.x;
  int j2 = t & 63, strm = t >> 6;
  int base = blockIdx.x * 256;
  float ax = 0.f, ay = 0.f, c = 0.f;
  int curb = -1;
  for (int i = 0; i < 64; ++i) {
    int n = base + strm + i * 4;
    if (n >= NND) break;
    int b = batch[n];
    if (b != curb) {
      if (curb >= 0) {
        atomicAdd(&pooled[curb * HD + 2 * j2], ax);
        atomicAdd(&pooled[curb * HD + 2 * j2 + 1], ay);
        if (j2 == 0) atomicAdd(&cnt[curb], c);
      }
      curb = b; ax = 0.f; ay = 0.f; c = 0.f;
    }
    unsigned u = gnn[(size_t)n * 64 + j2];
    ax += bflo(u);
    ay += bfhi(u);
    c += 1.f;
  }
  if (curb >= 0) {
    atomicAdd(&pooled[curb * HD + 2 * j2], ax);
    atomicAdd(&pooled[curb * HD + 2 * j2 + 1], ay);
    if (j2 == 0) atomicAdd(&cnt[curb], c);
  }
}

// ---------------- final ----------------
__global__ void k_final(const float* __restrict__ pooled,
                        const float* __restrict__ cnt,
                        const float* __restrict__ fin_w,
                        const float* __restrict__ fin_b,
                        float* __restrict__ out) {
  int w = threadIdx.x >> 6, lane = threadIdx.x & 63;
  for (int g = w; g < NGR; g += 4) {
    float2 pv = *(const float2*)&pooled[g * HD + lane * 2];
    float2 fw = *(const float2*)&fin_w[lane * 2];
    float s = pv.x * fw.x + pv.y * fw.y;
    for (int o = 32; o; o >>= 1) s += __shfl_xor(s, o);
    if (lane == 0) out[g] = s / fmaxf(cnt[g], 1.f) + fin_b[0];
  }
}

extern "C" void kernel_launch(void* const* d_in, const int* in_sizes, int n_in,
                              void* d_out, int out_size, void* d_ws, size_t ws_size,
                              hipStream_t stream) {
  const float* x       = (const float*)d_in[0];
  const int*   ei      = (const int*)d_in[1];
  const int*   batch   = (const int*)d_in[2];
  const float* W       = (const float*)d_in[3];
  const float* att_src = (const float*)d_in[4];
  const float* att_dst = (const float*)d_in[5];
  const float* bias    = (const float*)d_in[6];
  const float* fin_w   = (const float*)d_in[7];
  const float* fin_b   = (const float*)d_in[8];
  float* out = (float*)d_out;

  float*    a_s  = (float*)d_ws;                       // NND
  float*    a_d  = a_s + NND;                          // NND
  unsigned* h_bf = (unsigned*)(a_d + NND);             // NND*64
  unsigned* gnn  = h_bf + (size_t)NND * 64;            // NND*64
  uint2*    part = (uint2*)(gnn + (size_t)NND * 64);   // ET (8B-aligned offset)
  int*      esrc = (int*)(part + ET);                  // ET
  int*      off  = esrc + ET;                          // NND
  int*      deg  = off + NND;                          // NND
  int*      bsum = deg + NND;                          // 512
  int*      hist = bsum + 512;                         // PBLK*256
  int*      bkoff= hist + PBLK * 256;                  // 256
  int*      bkcnt= bkoff + 256;                        // 256
  float*  pooled = (float*)(bkcnt + 256);              // NGR*HD
  float*    cnt  = pooled + NGR * HD;                  // NGR
  unsigned short* WT = (unsigned short*)(cnt + NGR);   // 128*128 bf16 (16B-aligned)

  hipMemsetAsync(pooled, 0, (size_t)(NGR * HD + NGR) * 4, stream);

  k_wt   <<<64, 256, 0, stream>>>(W, WT);
  k_gemm <<<(NND + 63) / 64, 256, 0, stream>>>(x, WT, att_src, att_dst, h_bf, a_s, a_d);
  k_hist <<<PBLK, 1024, 0, stream>>>(ei, hist);
  k_hoff <<<1, 256, 0, stream>>>(hist, bkoff, bkcnt);
  k_part <<<PBLK, 1024, 0, stream>>>(ei, hist, part);
  k_bdeg <<<NBK, 256, 0, stream>>>(part, bkoff, bkcnt, deg);
  k_scan1<<<391, 256, 0, stream>>>(deg, off, bsum);
  k_scan2<<<1, 512, 0, stream>>>(bsum);
  k_scan3<<<391, 256, 0, stream>>>(bsum, off);
  k_bscat<<<NBK, 256, 0, stream>>>(part, bkoff, bkcnt, off, esrc);
  k_agg  <<<25000, 256, 0, stream>>>(off, deg, esrc, a_s, a_d, h_bf, bias, gnn);
  k_pool <<<391, 256, 0, stream>>>(gnn, batch, pooled, cnt);
  k_final<<<1, 256, 0, stream>>>(pooled, cnt, fin_w, fin_b, out);
}